// Round 1
// baseline (2292.227 us; speedup 1.0000x reference)
//
#include <hip/hip_runtime.h>
#include <hip/hip_bf16.h>

#define T_STEPS 64
#define B_DIM 2048
#define U_DIM 1024

#define BM 128
#define BN 64   // u-columns per block (each block computes f-half AND c-half)
#define BK 32
#define LDS_STRIDE 40  // 32 + 8 halfs padding -> 2-way bank aliasing (free)

typedef __attribute__((ext_vector_type(8))) _Float16 h8;
typedef __attribute__((ext_vector_type(4))) float f4;

// ---------------- init kernels ----------------

// R: [U][2U] f32 row-major  ->  Rt: [2U][U] f16 (i.e. B^T layout for MFMA B-frags)
__global__ void transpose_R(const float* __restrict__ R, _Float16* __restrict__ Rt) {
    __shared__ float tile[32][33];
    int nb = blockIdx.x * 32;   // n block (2U dim), gridDim.x = 64
    int kb = blockIdx.y * 32;   // k block (U dim),  gridDim.y = 32
    int tx = threadIdx.x, ty = threadIdx.y;   // block (32,8)
    #pragma unroll
    for (int i = ty; i < 32; i += 8)
        tile[i][tx] = R[(size_t)(kb + i) * (2 * U_DIM) + nb + tx];
    __syncthreads();
    #pragma unroll
    for (int i = ty; i < 32; i += 8)
        Rt[(size_t)(nb + i) * U_DIM + kb + tx] = (_Float16)tile[tx][i];
}

__global__ void init_state(const float* __restrict__ c0, _Float16* __restrict__ h0,
                           const float* __restrict__ x1_0, const float* __restrict__ x2_0,
                           float* __restrict__ x1w, float* __restrict__ x2w,
                           float* __restrict__ y) {
    int i = blockIdx.x * 256 + threadIdx.x;
    int n = B_DIM * U_DIM;
    for (int idx = i; idx < n; idx += gridDim.x * 256)
        h0[idx] = (_Float16)c0[idx];
    if (i < B_DIM) {
        x1w[i] = x1_0[i];
        x2w[i] = x2_0[i];
        y[i]   = 0.f;
    }
}

// ---------------- per-step fused GEMM + gates ----------------
// Computes for tile (b0..b0+127, u0..u0+63):
//   x_f = h@Rf + x1*Kf + bf ;  x_c = h@Rc + x1*Kc + bc
//   f = sigmoid(x_f); c = f*h + (1-f)*tanh(x_c)
//   hB[b][u] = c (f16);  y[b] += sum_u c*ok[u]  (atomic, partial)
__global__ __launch_bounds__(256) void gemm_step(
    const _Float16* __restrict__ hA,   // [B][U] current h (f16)
    _Float16* __restrict__ hB,         // [B][U] next h  (f16)
    const _Float16* __restrict__ Rt,   // [2U][U] (transposed recurrent kernel)
    const float* __restrict__ x1w,     // [B]
    const float* __restrict__ kern,    // [2U]
    const float* __restrict__ bias,    // [2U]
    const float* __restrict__ okern,   // [U]
    float* __restrict__ y)             // [B]
{
    __shared__ __align__(16) _Float16 lA [BM * LDS_STRIDE];
    __shared__ __align__(16) _Float16 lBf[BN * LDS_STRIDE];
    __shared__ __align__(16) _Float16 lBc[BN * LDS_STRIDE];

    const int tid    = threadIdx.x;
    const int wid    = tid >> 6;
    const int lane   = tid & 63;
    const int lane15 = lane & 15;
    const int quad   = lane >> 4;
    const int b0     = blockIdx.x * BM;
    const int u0     = blockIdx.y * BN;
    const int wrow   = wid >> 1;         // 0..1
    const int wcol   = wid & 1;          // 0..1
    const int moff   = wrow * 64;        // wave's row offset in tile
    const int noff   = wcol * 32;        // wave's u-col offset in tile

    f4 accF[4][2], accC[4][2];
    #pragma unroll
    for (int mt = 0; mt < 4; ++mt)
        #pragma unroll
        for (int nt = 0; nt < 2; ++nt) {
            accF[mt][nt] = (f4){0.f, 0.f, 0.f, 0.f};
            accC[mt][nt] = (f4){0.f, 0.f, 0.f, 0.f};
        }

    const int arow = tid >> 2;   // 0..63  (A rows arow, arow+64)
    const int ach  = tid & 3;    // 16B chunk within 64B row

    for (int kt = 0; kt < U_DIM / BK; ++kt) {
        const int k0 = kt * BK;
        // ---- stage A tile: 128 rows x 32 halfs ----
        #pragma unroll
        for (int i = 0; i < 2; ++i) {
            const int row = arow + i * 64;
            const uint4 v = *(const uint4*)&hA[(size_t)(b0 + row) * U_DIM + k0 + ach * 8];
            *(uint4*)&lA[row * LDS_STRIDE + ach * 8] = v;
        }
        // ---- stage B tiles (f and c halves): 64 rows x 32 halfs each ----
        {
            const uint4 vf = *(const uint4*)&Rt[(size_t)(u0 + arow) * U_DIM + k0 + ach * 8];
            *(uint4*)&lBf[arow * LDS_STRIDE + ach * 8] = vf;
            const uint4 vc = *(const uint4*)&Rt[(size_t)(U_DIM + u0 + arow) * U_DIM + k0 + ach * 8];
            *(uint4*)&lBc[arow * LDS_STRIDE + ach * 8] = vc;
        }
        __syncthreads();

        h8 af[4], bff[2], bfc[2];
        #pragma unroll
        for (int mt = 0; mt < 4; ++mt)
            af[mt] = *(const h8*)&lA[(moff + mt * 16 + lane15) * LDS_STRIDE + quad * 8];
        #pragma unroll
        for (int nt = 0; nt < 2; ++nt) {
            bff[nt] = *(const h8*)&lBf[(noff + nt * 16 + lane15) * LDS_STRIDE + quad * 8];
            bfc[nt] = *(const h8*)&lBc[(noff + nt * 16 + lane15) * LDS_STRIDE + quad * 8];
        }
        #pragma unroll
        for (int mt = 0; mt < 4; ++mt)
            #pragma unroll
            for (int nt = 0; nt < 2; ++nt) {
                accF[mt][nt] = __builtin_amdgcn_mfma_f32_16x16x32_f16(af[mt], bff[nt], accF[mt][nt], 0, 0, 0);
                accC[mt][nt] = __builtin_amdgcn_mfma_f32_16x16x32_f16(af[mt], bfc[nt], accC[mt][nt], 0, 0, 0);
            }
        __syncthreads();
    }

    // ---- epilogue: gates, c write, partial y ----
    #pragma unroll
    for (int mt = 0; mt < 4; ++mt) {
        const int b_base = b0 + moff + mt * 16 + quad * 4;
        float psum[4] = {0.f, 0.f, 0.f, 0.f};
        #pragma unroll
        for (int nt = 0; nt < 2; ++nt) {
            const int u = u0 + noff + nt * 16 + lane15;
            const float kf  = kern[u];
            const float kc  = kern[U_DIM + u];
            const float bfv = bias[u];
            const float bcv = bias[U_DIM + u];
            const float ok  = okern[u];
            #pragma unroll
            for (int reg = 0; reg < 4; ++reg) {
                const int b = b_base + reg;
                const float x1 = x1w[b];
                const float xf = accF[mt][nt][reg] + x1 * kf + bfv;
                const float xc = accC[mt][nt][reg] + x1 * kc + bcv;
                const float fg = 1.f / (1.f + __expf(-xf));
                const float hv = (float)hA[(size_t)b * U_DIM + u];
                const float cv = fg * hv + (1.f - fg) * tanhf(xc);
                hB[(size_t)b * U_DIM + u] = (_Float16)cv;
                psum[reg] += cv * ok;
            }
        }
        #pragma unroll
        for (int reg = 0; reg < 4; ++reg) {
            float s = psum[reg];
            s += __shfl_xor(s, 1);
            s += __shfl_xor(s, 2);
            s += __shfl_xor(s, 4);
            s += __shfl_xor(s, 8);
            if (lane15 == 0) atomicAdd(&y[b_base + reg], s);
        }
    }
}

// ---------------- per-step state update ----------------
__global__ void step_update(const float* __restrict__ inp_t,
                            float* __restrict__ x1w, float* __restrict__ x2w,
                            float* __restrict__ y, float* __restrict__ out_t) {
    const int b = blockIdx.x * 256 + threadIdx.x;
    const float x1 = x1w[b];
    const float x2 = x2w[b];
    const float yv = y[b];
    const float x1n = x1 + x2;
    const float x2n = x2 + inp_t[b] * yv;
    x1w[b] = x1n;
    x2w[b] = x2n;
    out_t[b] = x1n;
    y[b] = 0.f;   // ready for next step's atomics
}

// ---------------- host ----------------
extern "C" void kernel_launch(void* const* d_in, const int* in_sizes, int n_in,
                              void* d_out, int out_size, void* d_ws, size_t ws_size,
                              hipStream_t stream) {
    const float* inputs = (const float*)d_in[0];   // T*B
    const float* x1_0   = (const float*)d_in[1];   // B
    const float* x2_0   = (const float*)d_in[2];   // B
    const float* c0     = (const float*)d_in[3];   // B*U
    const float* kern   = (const float*)d_in[4];   // 2U
    const float* rker   = (const float*)d_in[5];   // U*2U
    const float* bias   = (const float*)d_in[6];   // 2U
    const float* okern  = (const float*)d_in[7];   // U
    float* out = (float*)d_out;                    // T*B

    // workspace layout
    _Float16* Rt = (_Float16*)d_ws;                         // 2U*U halfs = 4MB
    _Float16* h0 = Rt + (size_t)2 * U_DIM * U_DIM;          // B*U halfs  = 4MB
    _Float16* h1 = h0 + (size_t)B_DIM * U_DIM;              // B*U halfs  = 4MB
    float* x1w = (float*)(h1 + (size_t)B_DIM * U_DIM);
    float* x2w = x1w + B_DIM;
    float* y   = x2w + B_DIM;

    transpose_R<<<dim3(64, 32), dim3(32, 8), 0, stream>>>(rker, Rt);
    init_state<<<dim3(8192), dim3(256), 0, stream>>>(c0, h0, x1_0, x2_0, x1w, x2w, y);

    _Float16* hcur = h0;
    _Float16* hnxt = h1;
    for (int t = 0; t < T_STEPS; ++t) {
        gemm_step<<<dim3(B_DIM / BM, U_DIM / BN), dim3(256), 0, stream>>>(
            hcur, hnxt, Rt, x1w, kern, bias, okern, y);
        step_update<<<dim3(B_DIM / 256), dim3(256), 0, stream>>>(
            inputs + (size_t)t * B_DIM, x1w, x2w, y, out + (size_t)t * B_DIM);
        _Float16* tmp = hcur; hcur = hnxt; hnxt = tmp;
    }
}